// Round 3
// baseline (128.400 us; speedup 1.0000x reference)
//
#include <hip/hip_runtime.h>
#include <hip/hip_bf16.h>
#include <type_traits>

#define HID   128
#define PBLK  64
#define NPIX  (256*512)
#define L2E2  2.88539008177792681f   // 2*log2(e)

typedef __attribute__((ext_vector_type(8))) short bf16x8;
typedef __attribute__((ext_vector_type(4))) float f32x4;

__device__ inline unsigned pack2(float a, float b) {
    __hip_bfloat16 lo = __float2bfloat16(a);
    __hip_bfloat16 hi = __float2bfloat16(b);
    unsigned short ul = *reinterpret_cast<unsigned short*>(&lo);
    unsigned short uh = *reinterpret_cast<unsigned short*>(&hi);
    return (unsigned)ul | ((unsigned)uh << 16);
}
__device__ inline float ulo(unsigned u) { union { unsigned u; float f; } v; v.u = u << 16;        return v.f; }
__device__ inline float uhi(unsigned u) { union { unsigned u; float f; } v; v.u = u & 0xffff0000u; return v.f; }

// tanh(z) where u = 2*log2e*z (constant folded by caller)
__device__ inline float actf(float u) {
    float e = exp2f(u);
    return 1.0f - 2.0f * __builtin_amdgcn_rcpf(e + 1.0f);
}

__global__ __launch_bounds__(512, 4) void fused_net(
    const float* __restrict__ x_in,     // [3][NPIX]
    const float* __restrict__ W_in,     // [128][3]
    const float* __restrict__ W_h,      // [2][128][128]
    const float* __restrict__ r_rec,    // [3][128]
    const float* __restrict__ resp,     // [3][128]
    const float* __restrict__ bias,     // [3][128]
    const float* __restrict__ W_out,    // [3][128]
    const float* __restrict__ resp_out, // [3]
    const float* __restrict__ b_out,    // [3]
    const int*   __restrict__ n_iters_p,
    float* __restrict__ out)            // [3][NPIX]
{
    // Fragment-ordered LDS planes: chunk c at byte c*16, GEMM lane l reads chunk base+l.
    __shared__ __align__(16) unsigned short P0s[4 * 4 * 64 * 8];   // 16384 B
    __shared__ __align__(16) unsigned short P1s[4 * 4 * 64 * 8];   // 16384 B
    __shared__ __align__(16) unsigned short Wo_s[4 * 64 * 8];      //  4096 B
    __shared__ float4 Winp_s[HID];      // {a*w0, a*w1, a*w2, gamma}, a=2log2e*resp0
    __shared__ float4 sp_s[3 * HID];    // {alpha', beta', gamma', -} (folded 2log2e)
    __shared__ float  xs[3 * PBLK];
    __shared__ float  spo_s[8];

    const int t = threadIdx.x;
    const int w = t >> 6, l = t & 63;
    const int lr = l & 15, lg = l >> 4;
    const int rt2 = w >> 1;            // row-tile 0..3 (32 rows)
    const int ct  = w & 1;             // px-tile 0..1 (32 px)
    const int pixbase = (int)blockIdx.x * PBLK;
    const int niters = *n_iters_p;

    // ---- A-fragments (both layers' W rows for this wave) -> registers, bf16 ----
    bf16x8 A0[2][4], A1[2][4];
    #pragma unroll
    for (int lay = 0; lay < 2; ++lay) {
        #pragma unroll
        for (int kb = 0; kb < 4; ++kb) {
            const float* s0 = W_h + ((lay * HID + rt2 * 32 + lr) * HID + kb * 32 + lg * 8);
            const float* s1 = s0 + 16 * HID;
            float4 f0 = *(const float4*)s0, f1 = *(const float4*)(s0 + 4);
            float4 g0 = *(const float4*)s1, g1 = *(const float4*)(s1 + 4);
            uint4 va, vb;
            va.x = pack2(f0.x, f0.y); va.y = pack2(f0.z, f0.w);
            va.z = pack2(f1.x, f1.y); va.w = pack2(f1.z, f1.w);
            vb.x = pack2(g0.x, g0.y); vb.y = pack2(g0.z, g0.w);
            vb.z = pack2(g1.x, g1.y); vb.w = pack2(g1.z, g1.w);
            A0[lay][kb] = __builtin_bit_cast(bf16x8, va);
            A1[lay][kb] = __builtin_bit_cast(bf16x8, vb);
        }
    }

    // ---- stage small params into LDS ----
    if (t < 256) {                      // W_out padded to 16 rows, frag-ordered bf16
        int ll = t & 63, kb = t >> 6;
        int row = ll & 15, k = kb * 32 + (ll >> 4) * 8;
        uint4 v = {0u, 0u, 0u, 0u};
        if (row < 3) {
            const float* src = W_out + row * HID + k;
            float4 f0 = *(const float4*)src, f1 = *(const float4*)(src + 4);
            v.x = pack2(f0.x, f0.y); v.y = pack2(f0.z, f0.w);
            v.z = pack2(f1.x, f1.y); v.w = pack2(f1.z, f1.w);
        }
        *(uint4*)(Wo_s + t * 8) = v;
    }
    if (t < 3 * HID) {
        float rp = resp[t];
        float4 pv;
        pv.x = L2E2 * rp;
        pv.y = L2E2 * rp * r_rec[t];
        pv.z = L2E2 * bias[t];
        pv.w = 0.0f;
        sp_s[t] = pv;
    }
    if (t < HID) {
        float a = L2E2 * resp[t];
        float4 pv;
        pv.x = a * W_in[t * 3 + 0];
        pv.y = a * W_in[t * 3 + 1];
        pv.z = a * W_in[t * 3 + 2];
        pv.w = L2E2 * bias[t];
        Winp_s[t] = pv;
    }
    if (t < 3 * PBLK) xs[t] = x_in[(t >> 6) * NPIX + pixbase + (t & 63)];
    if (t < 3) { spo_s[t * 2] = L2E2 * resp_out[t]; spo_s[t * 2 + 1] = L2E2 * b_out[t]; }
    __syncthreads();

    const int p0 = t & 63, hb2 = t >> 6;
    const float x0 = xs[p0], x1 = xs[64 + p0], x2 = xs[128 + p0];

    unsigned rec0[8], rec1[8], rec2[8];
    #pragma unroll
    for (int i = 0; i < 8; ++i) { rec0[i] = 0u; rec1[i] = 0u; rec2[i] = 0u; }

    const bf16x8* P0c = (const bf16x8*)P0s;
    const bf16x8* P1c = (const bf16x8*)P1s;

    auto do_layer = [&](auto LAYC, const bf16x8* Sc, unsigned short* Dbase,
                        const float4* spL, unsigned* rec, bool dowrite) {
        constexpr int LAY = decltype(LAYC)::value;
        f32x4 acc00{0,0,0,0}, acc01{0,0,0,0}, acc10{0,0,0,0}, acc11{0,0,0,0};
        const bf16x8* SB = Sc + (ct * 2 * 4) * 64 + l;
        #pragma unroll
        for (int kb = 0; kb < 4; ++kb) {
            bf16x8 b0 = SB[kb * 64];
            bf16x8 b1 = SB[(4 + kb) * 64];
            acc00 = __builtin_amdgcn_mfma_f32_16x16x32_bf16(A0[LAY][kb], b0, acc00, 0, 0, 0);
            acc01 = __builtin_amdgcn_mfma_f32_16x16x32_bf16(A0[LAY][kb], b1, acc01, 0, 0, 0);
            acc10 = __builtin_amdgcn_mfma_f32_16x16x32_bf16(A1[LAY][kb], b0, acc10, 0, 0, 0);
            acc11 = __builtin_amdgcn_mfma_f32_16x16x32_bf16(A1[LAY][kb], b1, acc11, 0, 0, 0);
        }
        #pragma unroll
        for (int mt = 0; mt < 2; ++mt) {
            float4 prm[4];
            #pragma unroll
            for (int r = 0; r < 4; ++r) prm[r] = spL[rt2 * 32 + mt * 16 + lg * 4 + r];
            #pragma unroll
            for (int nt = 0; nt < 2; ++nt) {
                f32x4 a = mt ? (nt ? acc11 : acc10) : (nt ? acc01 : acc00);
                const int di = mt * 4 + nt * 2;
                float r0 = ulo(rec[di]),     r1 = uhi(rec[di]);
                float r2 = ulo(rec[di + 1]), r3 = uhi(rec[di + 1]);
                float v0 = actf(prm[0].x * a[0] + prm[0].y * r0 + prm[0].z);
                float v1 = actf(prm[1].x * a[1] + prm[1].y * r1 + prm[1].z);
                float v2 = actf(prm[2].x * a[2] + prm[2].y * r2 + prm[2].z);
                float v3 = actf(prm[3].x * a[3] + prm[3].y * r3 + prm[3].z);
                unsigned d0 = pack2(v0, v1), d1 = pack2(v2, v3);
                rec[di] = d0; rec[di + 1] = d1;
                if (dowrite) {
                    int chunk = ((ct * 2 + nt) * 4 + rt2) * 64 + (2 * mt + (lg >> 1)) * 16 + lr;
                    uint2 v; v.x = d0; v.y = d1;
                    *(uint2*)(Dbase + chunk * 8 + (lg & 1) * 4) = v;
                }
            }
        }
    };

    for (int it = 0; it < niters; ++it) {
        // ---- L0: leaves -> h0 (VALU, c1 recomputed via LDS broadcasts), write P0 ----
        #pragma unroll
        for (int s = 0; s < 2; ++s) {
            uint4 ov;
            #pragma unroll
            for (int q = 0; q < 4; ++q) {
                int c = s * 8 + q * 2, h = hb2 * 16 + c;
                float4 wp0 = Winp_s[h], wp1 = Winp_s[h + 1];
                float bet0 = sp_s[h].y, bet1 = sp_s[h + 1].y;
                unsigned rp = rec0[s * 4 + q];
                float c1a = fmaf(wp0.x, x0, fmaf(wp0.y, x1, fmaf(wp0.z, x2, wp0.w)));
                float c1b = fmaf(wp1.x, x0, fmaf(wp1.y, x1, fmaf(wp1.z, x2, wp1.w)));
                float v0 = actf(fmaf(bet0, ulo(rp), c1a));
                float v1 = actf(fmaf(bet1, uhi(rp), c1b));
                unsigned pk = pack2(v0, v1);
                rec0[s * 4 + q] = pk;
                if (q == 0) ov.x = pk; else if (q == 1) ov.y = pk;
                else if (q == 2) ov.z = pk; else ov.w = pk;
            }
            int h8 = hb2 * 16 + s * 8;
            int chunk = ((p0 >> 4) * 4 + (h8 >> 5)) * 64 + ((h8 >> 3) & 3) * 16 + (p0 & 15);
            *(uint4*)(P0s + chunk * 8) = ov;
        }
        __syncthreads();

        // ---- layer 1: P0 -> P1 ----
        do_layer(std::integral_constant<int,0>{}, P0c, P1s, sp_s + HID, rec1, true);
        __syncthreads();

        // ---- layer 2: P1 -> P0 (LDS write + barrier only needed on last iter) ----
        bool last = (it == niters - 1);
        do_layer(std::integral_constant<int,1>{}, P1c, P0s, sp_s + 2 * HID, rec2, last);
        if (last) __syncthreads();
    }

    // ---- output layer: waves 0..3, one 16-px group each ----
    if (w < 4) {
        f32x4 acc{0, 0, 0, 0};
        const bf16x8* OA = (const bf16x8*)Wo_s + l;
        const bf16x8* OB = P0c + (w * 4) * 64 + l;
        #pragma unroll
        for (int kb = 0; kb < 4; ++kb)
            acc = __builtin_amdgcn_mfma_f32_16x16x32_bf16(OA[kb * 64], OB[kb * 64], acc, 0, 0, 0);
        int p = pixbase + w * 16 + lr;
        #pragma unroll
        for (int r = 0; r < 4; ++r) {
            int o = lg * 4 + r;
            if (o < 3) out[o * NPIX + p] = actf(spo_s[o * 2] * acc[r] + spo_s[o * 2 + 1]);
        }
    }
}

extern "C" void kernel_launch(void* const* d_in, const int* in_sizes, int n_in,
                              void* d_out, int out_size, void* d_ws, size_t ws_size,
                              hipStream_t stream) {
    const float* x_in     = (const float*)d_in[0];
    const float* W_in     = (const float*)d_in[1];
    const float* W_h      = (const float*)d_in[2];
    const float* r_rec    = (const float*)d_in[3];
    const float* resp     = (const float*)d_in[4];
    const float* bias     = (const float*)d_in[5];
    const float* W_out    = (const float*)d_in[6];
    const float* resp_out = (const float*)d_in[7];
    const float* b_out    = (const float*)d_in[8];
    const int*   n_iters  = (const int*)d_in[9];
    float* out = (float*)d_out;

    dim3 grid(NPIX / PBLK);   // 2048 blocks
    dim3 block(512);
    fused_net<<<grid, block, 0, stream>>>(x_in, W_in, W_h, r_rec, resp, bias,
                                          W_out, resp_out, b_out, n_iters, out);
}

// Round 4
// 75.257 us; speedup vs baseline: 1.7062x; 1.7062x over previous
//
#include <hip/hip_runtime.h>
#include <hip/hip_bf16.h>

#define HID   128
#define PBLK  64
#define NPIX  (256*512)
#define L2E2  2.88539008177792681f   // 2*log2(e)

typedef __attribute__((ext_vector_type(8))) short bf16x8;
typedef __attribute__((ext_vector_type(4))) float f32x4;

__device__ inline unsigned pack2(float a, float b) {
    __hip_bfloat16 lo = __float2bfloat16(a);
    __hip_bfloat16 hi = __float2bfloat16(b);
    unsigned short ul = *reinterpret_cast<unsigned short*>(&lo);
    unsigned short uh = *reinterpret_cast<unsigned short*>(&hi);
    return (unsigned)ul | ((unsigned)uh << 16);
}
__device__ inline float ulo(unsigned u) { union { unsigned u; float f; } v; v.u = u << 16;        return v.f; }
__device__ inline float uhi(unsigned u) { union { unsigned u; float f; } v; v.u = u & 0xffff0000u; return v.f; }

// tanh(z) where u = 2*log2e*z (constants pre-folded)
__device__ inline float actf(float u) {
    float e = exp2f(u);
    return 1.0f - 2.0f * __builtin_amdgcn_rcpf(e + 1.0f);
}

// ---- prologue: W_h / W_out -> frag-ordered bf16 in workspace ----
// A chunk# = ((lay*4 + rt2)*2 + aidx)*4 + kb ; chunk holds 8 bf16 per lane slot l:
//   W_h[lay][rt2*32 + aidx*16 + (l&15)][kb*32 + (l>>4)*8 .. +8]
// W_out chunks (16-row zero-padded) start at ushort offset 32768.
__global__ __launch_bounds__(256) void prep_weights(
    const float* __restrict__ W_h, const float* __restrict__ W_out,
    unsigned short* __restrict__ ws)
{
    int c = blockIdx.x * 256 + threadIdx.x;
    if (c < 4096) {
        int l = c & 63, kb = (c >> 6) & 3, aidx = (c >> 8) & 1, rt2 = (c >> 9) & 3, lay = (c >> 11) & 1;
        int row = rt2 * 32 + aidx * 16 + (l & 15);
        int k   = kb * 32 + (l >> 4) * 8;
        const float* src = W_h + (lay * HID + row) * HID + k;
        float4 f0 = *(const float4*)src, f1 = *(const float4*)(src + 4);
        uint4 v;
        v.x = pack2(f0.x, f0.y); v.y = pack2(f0.z, f0.w);
        v.z = pack2(f1.x, f1.y); v.w = pack2(f1.z, f1.w);
        *(uint4*)(ws + (size_t)c * 8) = v;
    } else if (c < 4352) {
        int c2 = c - 4096, l = c2 & 63, kb = c2 >> 6;
        int row = l & 15, k = kb * 32 + (l >> 4) * 8;
        uint4 v = {0u, 0u, 0u, 0u};
        if (row < 3) {
            const float* src = W_out + row * HID + k;
            float4 f0 = *(const float4*)src, f1 = *(const float4*)(src + 4);
            v.x = pack2(f0.x, f0.y); v.y = pack2(f0.z, f0.w);
            v.z = pack2(f1.x, f1.y); v.w = pack2(f1.z, f1.w);
        }
        *(uint4*)(ws + 32768 + (size_t)c2 * 8) = v;
    }
}

__global__ __launch_bounds__(512, 4) void fused_net(
    const float* __restrict__ x_in,     // [3][NPIX]
    const float* __restrict__ W_in,     // [128][3]
    const float* __restrict__ r_rec,    // [3][128]
    const float* __restrict__ resp,     // [3][128]
    const float* __restrict__ bias,     // [3][128]
    const float* __restrict__ resp_out, // [3]
    const float* __restrict__ b_out,    // [3]
    const int*   __restrict__ n_iters_p,
    const unsigned short* __restrict__ wsw,  // frag-ordered bf16 weights
    float* __restrict__ out)            // [3][NPIX]
{
    // Only activation planes + small params in LDS -> ~41 KB -> 2 blocks/CU.
    __shared__ __align__(16) unsigned short P0s[4 * 4 * 64 * 8];   // 16384 B
    __shared__ __align__(16) unsigned short P1s[4 * 4 * 64 * 8];   // 16384 B
    __shared__ float4 Winp_s[HID];      // {a*w0,a*w1,a*w2,gamma0}
    __shared__ float4 sp_s[3 * HID];    // {alpha',beta',gamma',-}
    __shared__ float  xs[3 * PBLK];
    __shared__ float  spo_s[8];

    const int t = threadIdx.x;
    const int w = t >> 6, l = t & 63;
    const int lr = l & 15, lg = l >> 4;
    const int rt2 = w >> 1;            // row-tile 0..3
    const int ct  = w & 1;             // px-tile 0..1
    const int pixbase = (int)blockIdx.x * PBLK;
    const int niters = *n_iters_p;

    if (t < 3 * HID) {
        float rp = resp[t];
        float4 pv;
        pv.x = L2E2 * rp;
        pv.y = L2E2 * rp * r_rec[t];
        pv.z = L2E2 * bias[t];
        pv.w = 0.0f;
        sp_s[t] = pv;
    }
    if (t < HID) {
        float a = L2E2 * resp[t];
        float4 pv;
        pv.x = a * W_in[t * 3 + 0];
        pv.y = a * W_in[t * 3 + 1];
        pv.z = a * W_in[t * 3 + 2];
        pv.w = L2E2 * bias[t];
        Winp_s[t] = pv;
    }
    if (t < 3 * PBLK) xs[t] = x_in[(t >> 6) * NPIX + pixbase + (t & 63)];
    if (t < 3) { spo_s[t * 2] = L2E2 * resp_out[t]; spo_s[t * 2 + 1] = L2E2 * b_out[t]; }
    __syncthreads();

    const int p0 = t & 63, hb2 = t >> 6;
    const float x0 = xs[p0], x1 = xs[64 + p0], x2 = xs[128 + p0];

    unsigned rec0[8], rec1[8], rec2[8];
    #pragma unroll
    for (int i = 0; i < 8; ++i) { rec0[i] = 0u; rec1[i] = 0u; rec2[i] = 0u; }

    const bf16x8* P0c = (const bf16x8*)P0s;
    const bf16x8* P1c = (const bf16x8*)P1s;
    const bf16x8* wsA = (const bf16x8*)wsw;
    const bf16x8* WA0 = wsA + rt2 * 512 + l;        // layer-0 frags for this wave
    const bf16x8* WA1 = wsA + (4 + rt2) * 512 + l;  // layer-1 frags

    bf16x8 A[8];
    f32x4  acc[4];

    auto loadA = [&](const bf16x8* WA) {
        #pragma unroll
        for (int i = 0; i < 8; ++i) A[i] = WA[i * 64];   // coalesced 1KB dwordx4 loads
    };
    auto mfma16 = [&](const bf16x8* Sc) {
        #pragma unroll
        for (int i = 0; i < 4; ++i) acc[i] = f32x4{0.f, 0.f, 0.f, 0.f};
        const bf16x8* SB = Sc + (ct * 8) * 64 + l;
        #pragma unroll
        for (int kb = 0; kb < 4; ++kb) {
            bf16x8 b0 = SB[kb * 64];
            bf16x8 b1 = SB[(4 + kb) * 64];
            acc[0] = __builtin_amdgcn_mfma_f32_16x16x32_bf16(A[kb],     b0, acc[0], 0, 0, 0);
            acc[1] = __builtin_amdgcn_mfma_f32_16x16x32_bf16(A[kb],     b1, acc[1], 0, 0, 0);
            acc[2] = __builtin_amdgcn_mfma_f32_16x16x32_bf16(A[4 + kb], b0, acc[2], 0, 0, 0);
            acc[3] = __builtin_amdgcn_mfma_f32_16x16x32_bf16(A[4 + kb], b1, acc[3], 0, 0, 0);
        }
    };
    auto epilogue = [&](const float4* spL, unsigned* rec, unsigned short* Dbase, bool dowrite) {
        #pragma unroll
        for (int mt = 0; mt < 2; ++mt) {
            float4 prm[4];
            #pragma unroll
            for (int r = 0; r < 4; ++r) prm[r] = spL[rt2 * 32 + mt * 16 + lg * 4 + r];
            #pragma unroll
            for (int nt = 0; nt < 2; ++nt) {
                f32x4 a = acc[mt * 2 + nt];
                const int di = mt * 4 + nt * 2;
                float r0 = ulo(rec[di]),     r1 = uhi(rec[di]);
                float r2 = ulo(rec[di + 1]), r3 = uhi(rec[di + 1]);
                float v0 = actf(fmaf(prm[0].x, a[0], fmaf(prm[0].y, r0, prm[0].z)));
                float v1 = actf(fmaf(prm[1].x, a[1], fmaf(prm[1].y, r1, prm[1].z)));
                float v2 = actf(fmaf(prm[2].x, a[2], fmaf(prm[2].y, r2, prm[2].z)));
                float v3 = actf(fmaf(prm[3].x, a[3], fmaf(prm[3].y, r3, prm[3].z)));
                unsigned d0 = pack2(v0, v1), d1 = pack2(v2, v3);
                rec[di] = d0; rec[di + 1] = d1;
                if (dowrite) {
                    int chunk = ((ct * 2 + nt) * 4 + rt2) * 64 + (2 * mt + (lg >> 1)) * 16 + lr;
                    uint2 vv; vv.x = d0; vv.y = d1;
                    *(uint2*)(Dbase + chunk * 8 + (lg & 1) * 4) = vv;
                }
            }
        }
    };

    loadA(WA0);   // prefetch layer-0 A across the L0 phase
    for (int it = 0; it < niters; ++it) {
        // ---- L0: leaves -> h0 (VALU), frag-ordered write into P0 ----
        #pragma unroll
        for (int s = 0; s < 2; ++s) {
            uint4 ov;
            #pragma unroll
            for (int q = 0; q < 4; ++q) {
                int c = s * 8 + q * 2, h = hb2 * 16 + c;
                float4 wp0 = Winp_s[h], wp1 = Winp_s[h + 1];
                float bet0 = sp_s[h].y, bet1 = sp_s[h + 1].y;
                unsigned rp = rec0[s * 4 + q];
                float c1a = fmaf(wp0.x, x0, fmaf(wp0.y, x1, fmaf(wp0.z, x2, wp0.w)));
                float c1b = fmaf(wp1.x, x0, fmaf(wp1.y, x1, fmaf(wp1.z, x2, wp1.w)));
                float v0 = actf(fmaf(bet0, ulo(rp), c1a));
                float v1 = actf(fmaf(bet1, uhi(rp), c1b));
                unsigned pk = pack2(v0, v1);
                rec0[s * 4 + q] = pk;
                if (q == 0) ov.x = pk; else if (q == 1) ov.y = pk;
                else if (q == 2) ov.z = pk; else ov.w = pk;
            }
            int h8 = hb2 * 16 + s * 8;
            int chunk = ((p0 >> 4) * 4 + (h8 >> 5)) * 64 + ((h8 >> 3) & 3) * 16 + (p0 & 15);
            *(uint4*)(P0s + chunk * 8) = ov;
        }
        __syncthreads();

        // ---- layer 1: P0 -> P1 (A(L2) load hides under epilogue) ----
        mfma16(P0c);
        loadA(WA1);
        epilogue(sp_s + HID, rec1, P1s, true);
        __syncthreads();

        // ---- layer 2: P1 -> P0 (write only on last iter) ----
        bool last = (it == niters - 1);
        mfma16(P1c);
        if (!last) loadA(WA0);
        epilogue(sp_s + 2 * HID, rec2, P0s, last);
        if (last) __syncthreads();
    }

    // ---- output layer: waves 0..3, one 16-px group each; W_out frags from ws ----
    if (w < 4) {
        f32x4 oacc{0.f, 0.f, 0.f, 0.f};
        const bf16x8* OA = wsA + 4096 + l;
        const bf16x8* OB = P0c + (w * 4) * 64 + l;
        #pragma unroll
        for (int kb = 0; kb < 4; ++kb)
            oacc = __builtin_amdgcn_mfma_f32_16x16x32_bf16(OA[kb * 64], OB[kb * 64], oacc, 0, 0, 0);
        int p = pixbase + w * 16 + lr;
        #pragma unroll
        for (int r = 0; r < 4; ++r) {
            int o = lg * 4 + r;
            if (o < 3) out[o * NPIX + p] = actf(fmaf(spo_s[o * 2], oacc[r], spo_s[o * 2 + 1]));
        }
    }
}

extern "C" void kernel_launch(void* const* d_in, const int* in_sizes, int n_in,
                              void* d_out, int out_size, void* d_ws, size_t ws_size,
                              hipStream_t stream) {
    const float* x_in     = (const float*)d_in[0];
    const float* W_in     = (const float*)d_in[1];
    const float* W_h      = (const float*)d_in[2];
    const float* r_rec    = (const float*)d_in[3];
    const float* resp     = (const float*)d_in[4];
    const float* bias     = (const float*)d_in[5];
    const float* W_out    = (const float*)d_in[6];
    const float* resp_out = (const float*)d_in[7];
    const float* b_out    = (const float*)d_in[8];
    const int*   n_iters  = (const int*)d_in[9];
    float* out = (float*)d_out;
    unsigned short* ws = (unsigned short*)d_ws;

    prep_weights<<<17, 256, 0, stream>>>(W_h, W_out, ws);
    fused_net<<<NPIX / PBLK, 512, 0, stream>>>(x_in, W_in, r_rec, resp, bias,
                                               resp_out, b_out, n_iters, ws, out);
}